// Round 1
// baseline (1005.836 us; speedup 1.0000x reference)
//
#include <hip/hip_runtime.h>
#include <math.h>

// Problem constants (shapes are fixed by the reference; sizes derived from in_sizes at launch)
// N=100000 nodes, E=1600000 edges, F_IN=10 (+2 idx cols), H=128, G=1000 graphs, GAP=3
#define H 128
#define GAPLEN 3
#define DIN 18   // 10 float feats + 4 ship emb + 4 nav emb

static inline int ceil_div(int a, int b){ return (a + b - 1) / b; }

// ---------------- feats = [x[:, :10], ship_emb[x[:,10]], nav_emb[x[:,11]]] ----------------
__global__ void build_feats_k(const float* __restrict__ x, const float* __restrict__ se,
                              const float* __restrict__ ne, float* __restrict__ f, int n){
  int i = blockIdx.x * 256 + threadIdx.x;
  if (i >= n) return;
  const float* xr = x + (size_t)i * 12;
  float* fr = f + (size_t)i * DIN;
#pragma unroll
  for (int c = 0; c < 10; ++c) fr[c] = xr[c];
  int st = (int)xr[10];
  int nv = (int)xr[11];
#pragma unroll
  for (int c = 0; c < 4; ++c){
    fr[10 + c] = se[st * 4 + c];
    fr[14 + c] = ne[nv * 4 + c];
  }
}

// ---------------- in-degree histogram over dst ----------------
__global__ void edge_hist_k(const int* __restrict__ ei, int* __restrict__ cnt, int E){
  int e = blockIdx.x * 256 + threadIdx.x;
  if (e >= E) return;
  atomicAdd(&cnt[ei[E + e]], 1);
}

__global__ void dis_k(const int* __restrict__ cnt, float* __restrict__ dis, int n){
  int i = blockIdx.x * 256 + threadIdx.x;
  if (i < n) dis[i] = rsqrtf((float)cnt[i] + 1.0f);
}

// ---------------- exclusive scan of cnt -> row_ptr (3-kernel, chunk=2048) ----------------
__global__ void scanA_k(const int* __restrict__ cnt, int* __restrict__ rp,
                        int* __restrict__ bsum, int n){
  __shared__ int sd[256];
  int t = threadIdx.x;
  int base = blockIdx.x * 2048 + t * 8;
  int v[8]; int ts = 0;
#pragma unroll
  for (int i = 0; i < 8; ++i){ int idx = base + i; v[i] = (idx < n) ? cnt[idx] : 0; ts += v[i]; }
  sd[t] = ts;
  __syncthreads();
  for (int off = 1; off < 256; off <<= 1){
    int add = (t >= off) ? sd[t - off] : 0;
    __syncthreads();
    sd[t] += add;
    __syncthreads();
  }
  int run = sd[t] - ts;  // exclusive prefix within block
#pragma unroll
  for (int i = 0; i < 8; ++i){ int idx = base + i; if (idx < n) rp[idx] = run; run += v[i]; }
  if (t == 0) bsum[blockIdx.x] = sd[255];
}

__global__ void scanB_k(const int* __restrict__ bsum, int* __restrict__ bscan, int nb){
  __shared__ int sd[64];
  int t = threadIdx.x;
  int v = (t < nb) ? bsum[t] : 0;
  sd[t] = v;
  __syncthreads();
  for (int off = 1; off < 64; off <<= 1){
    int add = (t >= off) ? sd[t - off] : 0;
    __syncthreads();
    sd[t] += add;
    __syncthreads();
  }
  if (t < nb) bscan[t] = sd[t] - v;
}

__global__ void scanC_k(int* __restrict__ rp, const int* __restrict__ bscan, int n){
  int i = blockIdx.x * 256 + threadIdx.x;
  if (i < n) rp[i] += bscan[i >> 11];
}

// ---------------- scatter edges into CSR buckets ----------------
__global__ void scatter_k(const int* __restrict__ ei, const int* __restrict__ rp,
                          int* __restrict__ cur, int* __restrict__ csr, int E){
  int e = blockIdx.x * 256 + threadIdx.x;
  if (e >= E) return;
  int d = ei[E + e];
  int p = atomicAdd(&cur[d], 1);
  csr[rp[d] + p] = ei[e];
}

// ---------------- aggregation, d=18 (layer 1 input) ----------------
// out[i] = dis[i] * (sum_{e in(i)} dis[src]*f[src] + dis[i]*f[i])
__global__ void agg18_k(const float* __restrict__ f, const float* __restrict__ dis,
                        const int* __restrict__ rp, const int* __restrict__ cnt,
                        const int* __restrict__ csr, float* __restrict__ out, int n){
  int node = blockIdx.x * 8 + (threadIdx.x >> 5);
  if (node >= n) return;
  int lane = threadIdx.x & 31;
  bool act = lane < DIN;
  int start = rp[node];
  int m = cnt[node];
  float acc = 0.f;
  for (int e = 0; e < m; ++e){
    int s = csr[start + e];
    float w = dis[s];
    if (act) acc += w * f[(size_t)s * DIN + lane];
  }
  float di = dis[node];
  if (act){
    float self = f[(size_t)node * DIN + lane];
    out[(size_t)node * DIN + lane] = di * (acc + di * self);
  }
}

// ---------------- aggregation, d=128 ----------------
__global__ void agg128_k(const float* __restrict__ h, const float* __restrict__ dis,
                         const int* __restrict__ rp, const int* __restrict__ cnt,
                         const int* __restrict__ csr, float* __restrict__ out, int n){
  int node = blockIdx.x * 8 + (threadIdx.x >> 5);
  if (node >= n) return;
  int lane = threadIdx.x & 31;
  const float4* h4 = (const float4*)h;
  int start = rp[node];
  int m = cnt[node];
  float ax = 0.f, ay = 0.f, az = 0.f, aw = 0.f;
  int e = 0;
  for (; e + 1 < m; e += 2){
    int s0 = csr[start + e];
    int s1 = csr[start + e + 1];
    float w0 = dis[s0];
    float w1 = dis[s1];
    float4 v0 = h4[(size_t)s0 * 32 + lane];
    float4 v1 = h4[(size_t)s1 * 32 + lane];
    ax += w0 * v0.x + w1 * v1.x;
    ay += w0 * v0.y + w1 * v1.y;
    az += w0 * v0.z + w1 * v1.z;
    aw += w0 * v0.w + w1 * v1.w;
  }
  if (e < m){
    int s = csr[start + e];
    float w = dis[s];
    float4 v = h4[(size_t)s * 32 + lane];
    ax += w * v.x; ay += w * v.y; az += w * v.z; aw += w * v.w;
  }
  float di = dis[node];
  float4 hv = h4[(size_t)node * 32 + lane];
  float4 o;
  o.x = di * (ax + di * hv.x);
  o.y = di * (ay + di * hv.y);
  o.z = di * (az + di * hv.z);
  o.w = di * (aw + di * hv.w);
  ((float4*)out)[(size_t)node * 32 + lane] = o;
}

// ---------------- GEMM: [n,18] @ [18,128] + bias, relu ----------------
__global__ void gemm18_k(const float* __restrict__ A, const float* __restrict__ W,
                         const float* __restrict__ b, float* __restrict__ C, int n){
  __shared__ float sw[DIN * H];
  __shared__ float sb[H];
  __shared__ float sa[8][DIN];
  int t = threadIdx.x;
  for (int i = t; i < DIN * H; i += 256) sw[i] = W[i];
  if (t < H) sb[t] = b[t];
  int row0 = blockIdx.x * 8;
  for (int i = t; i < 8 * DIN; i += 256){
    int r = i / DIN, c = i % DIN;
    int rr = row0 + r;
    sa[r][c] = (rr < n) ? A[(size_t)rr * DIN + c] : 0.f;
  }
  __syncthreads();
  int r = t >> 5, lane = t & 31;
  int row = row0 + r;
  if (row >= n) return;
  int c0 = lane * 4;
  float ox = sb[c0], oy = sb[c0 + 1], oz = sb[c0 + 2], ow = sb[c0 + 3];
#pragma unroll
  for (int k = 0; k < DIN; ++k){
    float a = sa[r][k];
    const float4 w = *(const float4*)&sw[k * H + c0];
    ox += a * w.x; oy += a * w.y; oz += a * w.z; ow += a * w.w;
  }
  float4 o;
  o.x = fmaxf(ox, 0.f); o.y = fmaxf(oy, 0.f); o.z = fmaxf(oz, 0.f); o.w = fmaxf(ow, 0.f);
  *(float4*)&C[(size_t)row * H + c0] = o;
}

// ---------------- GEMM: [n,128] @ [128,128] + bias, relu ----------------
// BM=64 rows/block, full 128 cols, 128 threads, 8x8 per thread. A staged
// transposed in LDS; B streamed from global (L2-resident, 64KB).
__global__ __launch_bounds__(128) void gemm128_k(const float* __restrict__ A,
                                                 const float* __restrict__ B,
                                                 const float* __restrict__ bias,
                                                 float* __restrict__ C, int n){
  __shared__ float sa[32][64];  // [k][row]
  int t = threadIdx.x;
  int row0 = blockIdx.x * 64;
  int tc = t & 15;   // col group: cols tc*8 .. tc*8+7
  int tr = t >> 4;   // row group: rows tr*8 .. tr*8+7
  float acc[8][8];
#pragma unroll
  for (int i = 0; i < 8; ++i)
#pragma unroll
    for (int j = 0; j < 8; ++j) acc[i][j] = 0.f;

  int lr = t >> 1;           // 0..63 (row in tile)
  int lc = (t & 1) * 16;     // 0 or 16 (k offset in tile)
  for (int k0 = 0; k0 < H; k0 += 32){
    const float* Ar = A + (size_t)(row0 + lr) * H + k0 + lc;
    bool rowok = (row0 + lr) < n;
    float4 v0, v1, v2, v3;
    if (rowok){
      v0 = *(const float4*)(Ar + 0);
      v1 = *(const float4*)(Ar + 4);
      v2 = *(const float4*)(Ar + 8);
      v3 = *(const float4*)(Ar + 12);
    } else {
      v0 = v1 = v2 = v3 = float4{0.f, 0.f, 0.f, 0.f};
    }
    __syncthreads();  // previous tile fully consumed
    float vv[16] = {v0.x, v0.y, v0.z, v0.w, v1.x, v1.y, v1.z, v1.w,
                    v2.x, v2.y, v2.z, v2.w, v3.x, v3.y, v3.z, v3.w};
#pragma unroll
    for (int i = 0; i < 16; ++i) sa[lc + i][lr] = vv[i];
    __syncthreads();

    const float* Bp = B + (size_t)k0 * H + tc * 8;
#pragma unroll
    for (int k = 0; k < 32; ++k){
      float4 b0 = *(const float4*)(Bp + (size_t)k * H);
      float4 b1 = *(const float4*)(Bp + (size_t)k * H + 4);
      float4 a0 = *(const float4*)&sa[k][tr * 8];
      float4 a1 = *(const float4*)&sa[k][tr * 8 + 4];
      float aa[8] = {a0.x, a0.y, a0.z, a0.w, a1.x, a1.y, a1.z, a1.w};
      float bb[8] = {b0.x, b0.y, b0.z, b0.w, b1.x, b1.y, b1.z, b1.w};
#pragma unroll
      for (int i = 0; i < 8; ++i)
#pragma unroll
        for (int j = 0; j < 8; ++j) acc[i][j] += aa[i] * bb[j];
    }
  }
  float bb[8];
#pragma unroll
  for (int j = 0; j < 8; ++j) bb[j] = bias[tc * 8 + j];
#pragma unroll
  for (int i = 0; i < 8; ++i){
    int row = row0 + tr * 8 + i;
    if (row < n){
      float4 o0, o1;
      o0.x = fmaxf(acc[i][0] + bb[0], 0.f);
      o0.y = fmaxf(acc[i][1] + bb[1], 0.f);
      o0.z = fmaxf(acc[i][2] + bb[2], 0.f);
      o0.w = fmaxf(acc[i][3] + bb[3], 0.f);
      o1.x = fmaxf(acc[i][4] + bb[4], 0.f);
      o1.y = fmaxf(acc[i][5] + bb[5], 0.f);
      o1.z = fmaxf(acc[i][6] + bb[6], 0.f);
      o1.w = fmaxf(acc[i][7] + bb[7], 0.f);
      float* Cp = C + (size_t)row * H + tc * 8;
      *(float4*)(Cp) = o0;
      *(float4*)(Cp + 4) = o1;
    }
  }
}

// ---------------- graph counts histogram + scan + gap gather ----------------
__global__ void ghist_k(const int* __restrict__ batch, int* __restrict__ gc, int n){
  int i = blockIdx.x * 256 + threadIdx.x;
  if (i < n) atomicAdd(&gc[batch[i]], 1);
}

__global__ void gscan_k(const int* __restrict__ gc, int* __restrict__ go, int G){
  __shared__ int sd[1024];
  int t = threadIdx.x;
  int v = (t < G) ? gc[t] : 0;
  sd[t] = v;
  __syncthreads();
  for (int off = 1; off < 1024; off <<= 1){
    int add = (t >= off) ? sd[t - off] : 0;
    __syncthreads();
    sd[t] += add;
    __syncthreads();
  }
  if (t < G) go[t] = sd[t] - v;
}

__global__ void gather_k(const float* __restrict__ h, const int* __restrict__ go,
                         const int* __restrict__ gap, float* __restrict__ inp,
                         float* __restrict__ hf, float* __restrict__ hb, int G){
  int g = blockIdx.x;
  int t = threadIdx.x;
  if (g >= G) return;
  int idx = go[g] + gap[0];
  float v = h[(size_t)idx * H + t];
  inp[(size_t)g * H + t] = v;
  hf[(size_t)g * H + t] = v;
  hb[(size_t)g * H + t] = v;
}

// ---------------- GRU step: updates hf (y=0) / hb (y=1) in place ----------------
__global__ __launch_bounds__(256) void gru_k(const float* __restrict__ inp,
                                             float* __restrict__ hf, float* __restrict__ hb,
                                             const float* __restrict__ Wih_f, const float* __restrict__ Whh_f,
                                             const float* __restrict__ bih_f, const float* __restrict__ bhh_f,
                                             const float* __restrict__ Wih_b, const float* __restrict__ Whh_b,
                                             const float* __restrict__ bih_b, const float* __restrict__ bhh_b,
                                             int G){
  int cell = blockIdx.y;
  const float* Wih = cell ? Wih_b : Wih_f;
  const float* Whh = cell ? Whh_b : Whh_f;
  const float* bih = cell ? bih_b : bih_f;
  const float* bhh = cell ? bhh_b : bhh_f;
  float* h = cell ? hb : hf;

  __shared__ float sx[16][H];
  __shared__ float sh[16][H];
  int g0 = blockIdx.x * 16;
  int t = threadIdx.x;
  for (int i = t; i < 16 * H; i += 256){
    int g = i >> 7, c = i & 127;
    int gg = g0 + g;
    sx[g][c] = (gg < G) ? inp[(size_t)gg * H + c] : 0.f;
    sh[g][c] = (gg < G) ? h[(size_t)gg * H + c] : 0.f;
  }
  __syncthreads();
  int j = t & 127;
  int gs = (t >> 7) * 8;
  float ar[8] = {0}, az[8] = {0}, an[8] = {0};
  float br[8] = {0}, bz[8] = {0}, bn[8] = {0};
  for (int k = 0; k < H; ++k){
    float wr = Wih[k * 384 + j];
    float wz = Wih[k * 384 + 128 + j];
    float wn = Wih[k * 384 + 256 + j];
    float ur = Whh[k * 384 + j];
    float uz = Whh[k * 384 + 128 + j];
    float un = Whh[k * 384 + 256 + j];
#pragma unroll
    for (int g = 0; g < 8; ++g){
      float xv = sx[gs + g][k];
      float hv = sh[gs + g][k];
      ar[g] += xv * wr; az[g] += xv * wz; an[g] += xv * wn;
      br[g] += hv * ur; bz[g] += hv * uz; bn[g] += hv * un;
    }
  }
  float bir = bih[j], biz = bih[128 + j], bin = bih[256 + j];
  float bhr = bhh[j], bhz = bhh[128 + j], bhn = bhh[256 + j];
#pragma unroll
  for (int g = 0; g < 8; ++g){
    int gg = g0 + gs + g;
    if (gg < G){
      float r = 1.f / (1.f + expf(-(ar[g] + bir + br[g] + bhr)));
      float z = 1.f / (1.f + expf(-(az[g] + biz + bz[g] + bhz)));
      float nn = tanhf(an[g] + bin + r * (bn[g] + bhn));
      float hv = sh[gs + g][j];
      h[(size_t)gg * H + j] = (1.f - z) * nn + z * hv;
    }
  }
}

// ---------------- post step: preds_t and new inp from out=[hf,hb] ----------------
__global__ __launch_bounds__(256) void post_k(const float* __restrict__ hf, const float* __restrict__ hb,
                                              const float* __restrict__ Wred, const float* __restrict__ bred,
                                              const float* __restrict__ Wh1, const float* __restrict__ bh1,
                                              const float* __restrict__ Wh2, const float* __restrict__ bh2,
                                              float* __restrict__ inp, float* __restrict__ out,
                                              int G, int tstep){
  __shared__ float so[16][256];
  __shared__ float st1[16][H];
  int g0 = blockIdx.x * 16;
  int t = threadIdx.x;
  for (int i = t; i < 16 * H; i += 256){
    int g = i >> 7, c = i & 127;
    int gg = g0 + g;
    so[g][c]       = (gg < G) ? hf[(size_t)gg * H + c] : 0.f;
    so[g][128 + c] = (gg < G) ? hb[(size_t)gg * H + c] : 0.f;
  }
  __syncthreads();
  int j = t & 127;
  int gs = (t >> 7) * 8;
  float a1[8] = {0}, a2[8] = {0};
  for (int k = 0; k < 256; ++k){
    float w1 = Wh1[k * H + j];
    float w2 = Wred[k * H + j];
#pragma unroll
    for (int g = 0; g < 8; ++g){
      float o = so[gs + g][k];
      a1[g] += o * w1;
      a2[g] += o * w2;
    }
  }
  float B1 = bh1[j], BR = bred[j];
#pragma unroll
  for (int g = 0; g < 8; ++g){
    int gg = g0 + gs + g;
    float t1 = fmaxf(a1[g] + B1, 0.f);
    st1[gs + g][j] = (gg < G) ? t1 : 0.f;
    if (gg < G) inp[(size_t)gg * H + j] = a2[g] + BR;
  }
  __syncthreads();
  if (t < 32){
    int g = t >> 1, o = t & 1;
    int gg = g0 + g;
    if (gg < G){
      float s = bh2[o];
#pragma unroll 8
      for (int k = 0; k < H; ++k) s += st1[g][k] * Wh2[k * 2 + o];
      out[((size_t)gg * GAPLEN + tstep) * 2 + o] = s;
    }
  }
}

// =======================================================================
extern "C" void kernel_launch(void* const* d_in, const int* in_sizes, int n_in,
                              void* d_out, int out_size, void* d_ws, size_t ws_size,
                              hipStream_t stream) {
  const float* x     = (const float*)d_in[0];
  const int*   ei    = (const int*)d_in[1];
  const int*   batch = (const int*)d_in[2];
  const float* semb  = (const float*)d_in[3];
  const float* nemb  = (const float*)d_in[4];
  const float* W1 = (const float*)d_in[5];  const float* b1 = (const float*)d_in[6];
  const float* W2 = (const float*)d_in[7];  const float* b2 = (const float*)d_in[8];
  const float* W3 = (const float*)d_in[9];  const float* b3 = (const float*)d_in[10];
  const float* Wih_f = (const float*)d_in[11]; const float* Whh_f = (const float*)d_in[12];
  const float* bih_f = (const float*)d_in[13]; const float* bhh_f = (const float*)d_in[14];
  const float* Wih_b = (const float*)d_in[15]; const float* Whh_b = (const float*)d_in[16];
  const float* bih_b = (const float*)d_in[17]; const float* bhh_b = (const float*)d_in[18];
  const float* Wred = (const float*)d_in[19]; const float* bred = (const float*)d_in[20];
  const float* Wh1  = (const float*)d_in[21]; const float* bh1  = (const float*)d_in[22];
  const float* Wh2  = (const float*)d_in[23]; const float* bh2  = (const float*)d_in[24];
  const int* gap = (const int*)d_in[26];

  int N = in_sizes[0] / 12;
  int E = in_sizes[1] / 2;
  int G = out_size / (GAPLEN * 2);
  float* out = (float*)d_out;

  char* ws = (char*)d_ws;
  size_t off = 0;
  auto alloc = [&](size_t bytes) -> void* {
    void* p = ws + off;
    off += (bytes + 511) & ~(size_t)511;
    return p;
  };
  float* feats  = (float*)alloc((size_t)N * DIN * 4);
  float* bufA   = (float*)alloc((size_t)N * H * 4);   // agg target (aggF lives in front)
  float* bufB   = (float*)alloc((size_t)N * H * 4);   // h target
  int*   cnt    = (int*)alloc((size_t)N * 4);
  float* dis    = (float*)alloc((size_t)N * 4);
  int*   rp     = (int*)alloc((size_t)N * 4);
  int*   cur    = (int*)alloc((size_t)N * 4);
  int*   csr    = (int*)alloc((size_t)E * 4);
  int*   bsum   = (int*)alloc(64 * 4);
  int*   bscan  = (int*)alloc(64 * 4);
  int*   gc     = (int*)alloc((size_t)G * 4);
  int*   go     = (int*)alloc((size_t)G * 4);
  float* ginp   = (float*)alloc((size_t)G * H * 4);
  float* ghf    = (float*)alloc((size_t)G * H * 4);
  float* ghb    = (float*)alloc((size_t)G * H * 4);
  (void)ws_size; (void)n_in;

  // zero the atomically-accumulated buffers every call (ws is not re-poisoned)
  hipMemsetAsync(cnt, 0, (size_t)N * 4, stream);
  hipMemsetAsync(cur, 0, (size_t)N * 4, stream);
  hipMemsetAsync(gc, 0, (size_t)G * 4, stream);

  int nb256  = ceil_div(N, 256);
  int eb256  = ceil_div(E, 256);
  int sb     = ceil_div(N, 2048);   // <= 64 for N <= 131072

  build_feats_k<<<nb256, 256, 0, stream>>>(x, semb, nemb, feats, N);
  edge_hist_k<<<eb256, 256, 0, stream>>>(ei, cnt, E);
  dis_k<<<nb256, 256, 0, stream>>>(cnt, dis, N);
  scanA_k<<<sb, 256, 0, stream>>>(cnt, rp, bsum, N);
  scanB_k<<<1, 64, 0, stream>>>(bsum, bscan, sb);
  scanC_k<<<nb256, 256, 0, stream>>>(rp, bscan, N);
  scatter_k<<<eb256, 256, 0, stream>>>(ei, rp, cur, csr, E);

  int aggb = ceil_div(N, 8);
  // layer 1: aggregate feats (18), GEMM 18->128 (+relu)
  agg18_k<<<aggb, 256, 0, stream>>>(feats, dis, rp, cnt, csr, bufA, N);
  gemm18_k<<<ceil_div(N, 8), 256, 0, stream>>>(bufA, W1, b1, bufB, N);
  // layer 2
  agg128_k<<<aggb, 256, 0, stream>>>(bufB, dis, rp, cnt, csr, bufA, N);
  gemm128_k<<<ceil_div(N, 64), 128, 0, stream>>>(bufA, W2, b2, bufB, N);
  // layer 3
  agg128_k<<<aggb, 256, 0, stream>>>(bufB, dis, rp, cnt, csr, bufA, N);
  gemm128_k<<<ceil_div(N, 64), 128, 0, stream>>>(bufA, W3, b3, bufB, N);

  // gap-node gather
  ghist_k<<<nb256, 256, 0, stream>>>(batch, gc, N);
  gscan_k<<<1, 1024, 0, stream>>>(gc, go, G);
  gather_k<<<G, H, 0, stream>>>(bufB, go, gap, ginp, ghf, ghb, G);

  // decoder: 3 steps
  int gb = ceil_div(G, 16);
  for (int t = 0; t < GAPLEN; ++t){
    gru_k<<<dim3(gb, 2), 256, 0, stream>>>(ginp, ghf, ghb,
                                           Wih_f, Whh_f, bih_f, bhh_f,
                                           Wih_b, Whh_b, bih_b, bhh_b, G);
    post_k<<<gb, 256, 0, stream>>>(ghf, ghb, Wred, bred, Wh1, bh1, Wh2, bh2,
                                   ginp, out, G, t);
  }
}